// Round 1
// baseline (154.241 us; speedup 1.0000x reference)
//
#include <hip/hip_runtime.h>
#include <hip/hip_bf16.h>
#include <math.h>

// Problem constants (match reference)
#define BB 8
#define LL 1024
#define DD 1024
#define KK 128
#define NTS 1000
#define SCALE 0.08838834764831845f                 // 128^-0.5

typedef __attribute__((ext_vector_type(8))) short short8;   // 8 bf16 = 4 VGPRs
typedef __attribute__((ext_vector_type(4))) float f32x4;    // MFMA accumulator

__device__ __forceinline__ unsigned short f2bf(float x) {
    __hip_bfloat16 h = __float2bfloat16(x);   // RTNE
    return *reinterpret_cast<unsigned short*>(&h);
}
__device__ __forceinline__ float bf2f(unsigned short u) {
    return __uint_as_float(((unsigned int)u) << 16);
}

// async global->LDS, 16B per lane, LDS dest = wave-uniform base + lane*16
__device__ __forceinline__ void gload_lds16(const void* g, void* l) {
    __builtin_amdgcn_global_load_lds(
        (const __attribute__((address_space(1))) unsigned int*)g,
        (__attribute__((address_space(3))) unsigned int*)l, 16, 0, 0);
}

// Per-phase LDS union for prep (16.4 KB max)
union SMem {
    float4 keys[LL];           // 16384 B (attention)
    float  tile[32][33];       // 4224 B  (transpose)
};

// ---------------------------------------------------------------------------
// 32x32 transpose+cast tile: in fp32 [1024,1024] -> out[n][k] bf16 (R6-proven)
// ---------------------------------------------------------------------------
__device__ __forceinline__ void transpose_tile(
    const float* __restrict__ in, unsigned short* __restrict__ out,
    int idx, SMem& sm)
{
    const int tid = threadIdx.x;
    const int bx = (idx & 31) * 32, by = (idx >> 5) * 32;
    const int tx = tid & 31, ty = tid >> 5;   // 32 x 8
    #pragma unroll
    for (int r = 0; r < 32; r += 8)
        sm.tile[ty + r][tx] = in[(size_t)(by + ty + r) * DD + bx + tx];
    __syncthreads();
    #pragma unroll
    for (int r = 0; r < 32; r += 8)
        out[(size_t)(bx + ty + r) * DD + by + tx] = f2bf(sm.tile[tx][ty + r]);
    __syncthreads();
}

// ---------------------------------------------------------------------------
// 64x64-tile BK=64 double-buffered MFMA GEMM.
//   - grid 256 blocks (16x16 tiles), 1 block/CU, 4 waves (2x2), each 32x32.
//   - B (and A when bf16) staged via global_load_lds dwordx4 (linear LDS dest,
//     inverse-swizzled global source); fragments read with the same XOR
//     swizzle: byte ^= ((row&7)<<4)  [rule 21: both-sides-or-neither].
//   - 2-phase pipeline: stage(t+1) issued BEFORE compute(t); one
//     vmcnt(0)+barrier per K-step so load latency hides under MFMA (T3-min).
//   - AF32: A fp32 (time_table), rows clamped at NTS-1, issue-early loads /
//     cast+ds_write late (T14 split). No Tbf intermediate needed.
// ---------------------------------------------------------------------------
template<bool AF32>
__device__ __forceinline__ void gemm64(
    const float* __restrict__ Af, const unsigned short* __restrict__ Ab,
    const unsigned short* __restrict__ Bt, const float* __restrict__ bias,
    unsigned short* __restrict__ Cout, int mBase, int nBase, bool do_silu)
{
    __shared__ __align__(16) unsigned short As[2][64 * 64];   // 8 KB each
    __shared__ __align__(16) unsigned short Bs[2][64 * 64];

    const int tid  = threadIdx.x;
    const int lane = tid & 63, wave = tid >> 6;
    const int wm = wave >> 1, wn = wave & 1;
    const int quad = lane >> 4, l16 = lane & 15;
    const int c0 = wave * 2;                  // this wave's 2 chunks (of 8)

    // Staging geometry: LDS linear byte o = c*1024 + lane*16; row = o>>7;
    // source element = o ^ ((row&7)<<4)  (XOR involution on bits 4-6; row
    // bits >=7 untouched, so read-side swizzle recovers it exactly).
    int rowA[2], kEl[2], rAc[2];
    #pragma unroll
    for (int i = 0; i < 2; ++i) {
        const int c   = c0 + i;
        const int o   = c * 1024 + lane * 16;
        const int row = o >> 7;
        const int lin = o ^ ((row & 7) << 4);
        rowA[i] = row;
        kEl[i]  = (lin & 127) >> 1;           // element offset, multiple of 8
        if (AF32) {
            int r = mBase + row;
            rAc[i] = r < NTS ? r : NTS - 1;   // clamp junk rows (never gathered)
        }
    }

    f32x4 acc[2][2];
    #pragma unroll
    for (int i = 0; i < 2; ++i)
        #pragma unroll
        for (int j = 0; j < 2; ++j)
            acc[i][j] = (f32x4){0.f, 0.f, 0.f, 0.f};

    float4 pa[2][2];

    // ---- prologue: stage tile 0 ----
    if (AF32) {
        #pragma unroll
        for (int i = 0; i < 2; ++i) {
            const float* p = Af + (size_t)rAc[i] * DD + kEl[i];
            pa[i][0] = *(const float4*)p;
            pa[i][1] = *(const float4*)(p + 4);
        }
    } else {
        #pragma unroll
        for (int i = 0; i < 2; ++i)
            gload_lds16(Ab + (size_t)(mBase + rowA[i]) * DD + kEl[i],
                        (char*)&As[0][0] + (c0 + i) * 1024);
    }
    #pragma unroll
    for (int i = 0; i < 2; ++i)
        gload_lds16(Bt + (size_t)(nBase + rowA[i]) * DD + kEl[i],
                    (char*)&Bs[0][0] + (c0 + i) * 1024);
    asm volatile("s_waitcnt vmcnt(0)" ::: "memory");
    if (AF32) {
        #pragma unroll
        for (int i = 0; i < 2; ++i) {
            short8 s;
            s[0] = f2bf(pa[i][0].x); s[1] = f2bf(pa[i][0].y);
            s[2] = f2bf(pa[i][0].z); s[3] = f2bf(pa[i][0].w);
            s[4] = f2bf(pa[i][1].x); s[5] = f2bf(pa[i][1].y);
            s[6] = f2bf(pa[i][1].z); s[7] = f2bf(pa[i][1].w);
            *(short8*)((char*)&As[0][0] + (c0 + i) * 1024 + lane * 16) = s;
        }
    }
    __syncthreads();

    int buf = 0;
    for (int t = 0; t < 16; ++t) {
        const int kn = (t + 1) * 64;
        if (t < 15) {
            // issue next-tile staging BEFORE compute (latency hides under MFMA)
            if (AF32) {
                #pragma unroll
                for (int i = 0; i < 2; ++i) {
                    const float* p = Af + (size_t)rAc[i] * DD + kn + kEl[i];
                    pa[i][0] = *(const float4*)p;
                    pa[i][1] = *(const float4*)(p + 4);
                }
            } else {
                #pragma unroll
                for (int i = 0; i < 2; ++i)
                    gload_lds16(Ab + (size_t)(mBase + rowA[i]) * DD + kn + kEl[i],
                                (char*)&As[buf ^ 1][0] + (c0 + i) * 1024);
            }
            #pragma unroll
            for (int i = 0; i < 2; ++i)
                gload_lds16(Bt + (size_t)(nBase + rowA[i]) * DD + kn + kEl[i],
                            (char*)&Bs[buf ^ 1][0] + (c0 + i) * 1024);
        }

        // compute on buf: 2 kk-steps x (4 ds_read_b128 + 4 MFMA)
        #pragma unroll
        for (int kk = 0; kk < 64; kk += 32) {
            short8 a[2], b[2];
            #pragma unroll
            for (int i = 0; i < 2; ++i) {
                const int row  = wm * 32 + i * 16 + l16;
                const int byte = ((row << 7) + ((kk + quad * 8) << 1))
                                 ^ ((row & 7) << 4);
                a[i] = *(const short8*)((const char*)&As[buf][0] + byte);
            }
            #pragma unroll
            for (int j = 0; j < 2; ++j) {
                const int row  = wn * 32 + j * 16 + l16;
                const int byte = ((row << 7) + ((kk + quad * 8) << 1))
                                 ^ ((row & 7) << 4);
                b[j] = *(const short8*)((const char*)&Bs[buf][0] + byte);
            }
            #pragma unroll
            for (int i = 0; i < 2; ++i)
                #pragma unroll
                for (int j = 0; j < 2; ++j)
                    acc[i][j] = __builtin_amdgcn_mfma_f32_16x16x32_bf16(
                                    a[i], b[j], acc[i][j], 0, 0, 0);
        }

        if (t < 15) {
            asm volatile("s_waitcnt vmcnt(0)" ::: "memory");
            if (AF32) {
                #pragma unroll
                for (int i = 0; i < 2; ++i) {
                    short8 s;
                    s[0] = f2bf(pa[i][0].x); s[1] = f2bf(pa[i][0].y);
                    s[2] = f2bf(pa[i][0].z); s[3] = f2bf(pa[i][0].w);
                    s[4] = f2bf(pa[i][1].x); s[5] = f2bf(pa[i][1].y);
                    s[6] = f2bf(pa[i][1].z); s[7] = f2bf(pa[i][1].w);
                    *(short8*)((char*)&As[buf ^ 1][0] + (c0 + i) * 1024 + lane * 16) = s;
                }
            }
            __syncthreads();
        }
        buf ^= 1;
    }

    // epilogue: C/D layout col = lane&15, row = quad*4 + reg  [m89-verified]
    #pragma unroll
    for (int j = 0; j < 2; ++j) {
        const int col = nBase + wn * 32 + j * 16 + l16;
        const float bv = bias[col];
        #pragma unroll
        for (int i = 0; i < 2; ++i) {
            #pragma unroll
            for (int r = 0; r < 4; ++r) {
                const int row = mBase + wm * 32 + i * 16 + quad * 4 + r;
                float val = acc[i][j][r] + bv;
                if (do_silu) val = val / (1.0f + __expf(-val));
                Cout[(size_t)row * DD + col] = f2bf(val);
            }
        }
    }
}

// ---------------------------------------------------------------------------
// K1 prep: all GEMM-independent work.
//   0..1023    : w1 -> W1t transpose tiles
//   1024..2047 : w2 -> W2t transpose tiles
//   2048..2207 : embed cast fp32->bf16
//   2208..2719 : atom cast fp32->bf16
//   2720..2723 : v[d] = sum_c pos_emb_w[c] * pos_feature_w[c,d]
//   2724       : is_molecule dtype resolve
//   2725..3236 : attention scalars (512 blocks x 16 queries -> sSg)
// ---------------------------------------------------------------------------
__global__ __launch_bounds__(256) void prep(
    const float* __restrict__ w1,
    const float* __restrict__ w2,
    const float* __restrict__ embed_f,
    const float* __restrict__ atom_f,
    const float* __restrict__ pos_emb_w,
    const float* __restrict__ pos_feature_w,
    const void*  __restrict__ is_mol_raw,
    const int*   __restrict__ token_id,
    const float* __restrict__ pos,
    unsigned short* __restrict__ W1t,
    unsigned short* __restrict__ W2t,
    unsigned short* __restrict__ embed_bf,
    unsigned short* __restrict__ atom_bf,
    float* __restrict__ v,
    int*   __restrict__ is_mol_out,
    float* __restrict__ sSg)
{
    __shared__ SMem sm;
    const int blk = blockIdx.x;
    const int tid = threadIdx.x;

    if (blk < 1024) {
        transpose_tile(w1, W1t, blk, sm);
    } else if (blk < 2048) {
        transpose_tile(w2, W2t, blk - 1024, sm);
    } else if (blk < 2208) {
        const int e = ((blk - 2048) * 256 + tid) * 4;    // < 160*1024
        float4 vv = *(const float4*)&embed_f[e];
        ushort4 o = { f2bf(vv.x), f2bf(vv.y), f2bf(vv.z), f2bf(vv.w) };
        *(ushort4*)&embed_bf[e] = o;
    } else if (blk < 2720) {
        const int e = ((blk - 2208) * 256 + tid) * 4;    // < 512*1024
        float4 vv = *(const float4*)&atom_f[e];
        ushort4 o = { f2bf(vv.x), f2bf(vv.y), f2bf(vv.z), f2bf(vv.w) };
        *(ushort4*)&atom_bf[e] = o;
    } else if (blk < 2724) {
        const int d = (blk - 2720) * 256 + tid;          // < 1024
        float acc = 0.0f;
        #pragma unroll 4
        for (int c = 0; c < KK; ++c)
            acc += pos_emb_w[c] * pos_feature_w[c * DD + d];
        v[d] = acc;
    } else if (blk == 2724) {
        if (tid == 0) {
            const int* ip = (const int*)is_mol_raw;
            const unsigned char* cp = (const unsigned char*)is_mol_raw;
            bool all_bin = true;
            for (int i = 0; i < BB; ++i) {
                int x = ip[i];
                if (x != 0 && x != 1) all_bin = false;
            }
            for (int i = 0; i < BB; ++i)
                is_mol_out[i] = all_bin ? (ip[i] != 0) : (cp[i] != 0);
        }
    } else {
        // Attention scalars: block handles 16 queries of one batch.
        // No-max softmax: valid scores in (0, 0.0884] so exp can't overflow;
        // masked keys contribute exactly 0 (reference: exp(NEG*SCALE-gmax)==0).
        const int ab = blk - 2725;            // 0..511
        const int batch = ab >> 6;
        const int q0 = (ab & 63) * 16;
        const int lane = tid & 63, wave = tid >> 6;

        #pragma unroll
        for (int i = 0; i < 4; ++i) {
            const int k = tid + i * 256;
            const int t = batch * LL + k;
            const float x = pos[t * 3 + 0];
            const float y = pos[t * 3 + 1];
            const float z = pos[t * 3 + 2];
            const int tok = token_id[t];
            const float n = sqrtf(x * x + y * y + z * z);
            sm.keys[k] = make_float4(x, y, z, tok == 0 ? -1.0f : n);
        }
        __syncthreads();

        #pragma unroll
        for (int qi = 0; qi < 4; ++qi) {
            const int ql = wave * 4 + qi;
            const float4 qk = sm.keys[q0 + ql];
            float lsum = 0.0f, lws = 0.0f;
            #pragma unroll 4
            for (int i = 0; i < 16; ++i) {
                const float4 kd = sm.keys[lane + i * 64];
                const float dx = qk.x - kd.x, dy = qk.y - kd.y, dz = qk.z - kd.z;
                const float dn = sqrtf(dx * dx + dy * dy + dz * dz);
                const float e = __expf(SCALE / (dn + 1.0f));
                const bool valid = kd.w >= 0.0f;
                const float ev = valid ? e : 0.0f;
                lsum += ev;
                lws  += ev * (valid ? kd.w : 0.0f);
            }
            #pragma unroll
            for (int off = 32; off > 0; off >>= 1) {
                lsum += __shfl_xor(lsum, off);
                lws  += __shfl_xor(lws,  off);
            }
            if (lane == 0)
                sSg[batch * LL + q0 + ql] = (qk.w < 0.0f) ? 0.0f : (lws / lsum);
        }
    }
}

// ---------------------------------------------------------------------------
// K2: gemm1 = silu(time_table @ W1 + b1) -> H bf16.  256 blocks (16x16 tiles),
// XCD-chunked swizzle (256%8==0, bijective): consecutive-dispatch blocks on
// one XCD share the same A-panel rows -> L2 locality.
// ---------------------------------------------------------------------------
__global__ __launch_bounds__(256) void gemm1k(
    const float* __restrict__ time_table,
    const unsigned short* __restrict__ W1t,
    const float* __restrict__ b1,
    unsigned short* __restrict__ H)
{
    const int b = (blockIdx.x & 7) * 32 + (blockIdx.x >> 3);
    gemm64<true>(time_table, nullptr, W1t, b1, H,
                 (b >> 4) * 64, (b & 15) * 64, true);
}

// ---------------------------------------------------------------------------
// K3: gemm2 = H @ W2 + b2 -> Ebf bf16 (overlays dead W1t).
// ---------------------------------------------------------------------------
__global__ __launch_bounds__(256) void gemm2k(
    const unsigned short* __restrict__ H,
    const unsigned short* __restrict__ W2t,
    const float* __restrict__ b2,
    unsigned short* __restrict__ Ebf)
{
    const int b = (blockIdx.x & 7) * 32 + (blockIdx.x >> 3);
    gemm64<false>(nullptr, H, W2t, b2, Ebf,
                  (b >> 4) * 64, (b & 15) * 64, false);
}

// ---------------------------------------------------------------------------
// K4: gather/assemble only (unchanged, R6-proven).
// 1024 blocks x 256 thr; block = 8 queries; 2 queries across thread halves.
// ---------------------------------------------------------------------------
__global__ __launch_bounds__(256) void assemble(
    const int*   __restrict__ token_id,
    const int*   __restrict__ node_attr,
    const int*   __restrict__ time_step,
    const unsigned short* __restrict__ embed_bf,
    const unsigned short* __restrict__ atom_bf,
    const unsigned short* __restrict__ Ebf,
    const float* __restrict__ v,
    const float* __restrict__ sSg,
    const int*   __restrict__ is_mol,
    float* __restrict__ out)
{
    const int blk   = blockIdx.x;
    const int batch = blk >> 7;
    const int q0    = (blk & 127) << 3;
    const int tid   = threadIdx.x;

    const int im   = is_mol[batch];
    const int half = tid >> 7;
    const int tl   = tid & 127;
    const int j    = tl * 8;
    const float4 v0 = *(const float4*)&v[j];
    const float4 v1 = *(const float4*)&v[j + 4];

    #pragma unroll
    for (int qp = 0; qp < 4; ++qp) {
        const int ql  = qp * 2 + half;
        const int t   = batch * LL + q0 + ql;
        const int tok = token_id[t];
        const int ts  = time_step[t];
        const float s = sSg[t];

        float o[8];
        short8 eb = *(const short8*)&embed_bf[(size_t)tok * DD + j];
        #pragma unroll
        for (int d = 0; d < 8; ++d) o[d] = bf2f((unsigned short)eb[d]);

        if (im) {
            #pragma unroll
            for (int f = 1; f < 9; ++f) {
                const int a = node_attr[t * 9 + f];
                short8 ab = *(const short8*)&atom_bf[(size_t)a * DD + j];
                #pragma unroll
                for (int d = 0; d < 8; ++d) o[d] += bf2f((unsigned short)ab[d]);
            }
        }
        short8 er = *(const short8*)&Ebf[(size_t)ts * DD + j];
        #pragma unroll
        for (int d = 0; d < 8; ++d) o[d] += bf2f((unsigned short)er[d]);

        o[0] += s * v0.x; o[1] += s * v0.y; o[2] += s * v0.z; o[3] += s * v0.w;
        o[4] += s * v1.x; o[5] += s * v1.y; o[6] += s * v1.z; o[7] += s * v1.w;

        float4 wlo = {o[0], o[1], o[2], o[3]};
        float4 whi = {o[4], o[5], o[6], o[7]};
        *(float4*)&out[(size_t)t * DD + j]     = wlo;
        *(float4*)&out[(size_t)t * DD + j + 4] = whi;
    }

    if (tid < 8) {
        const int t = batch * LL + q0 + tid;
        out[(size_t)BB * LL * DD + t] = (token_id[t] == 0) ? 1.0f : 0.0f;
    }
}

// ---------------------------------------------------------------------------
extern "C" void kernel_launch(void* const* d_in, const int* in_sizes, int n_in,
                              void* d_out, int out_size, void* d_ws, size_t ws_size,
                              hipStream_t stream)
{
    const int*   token_id      = (const int*)  d_in[0];
    const int*   node_attr     = (const int*)  d_in[1];
    const void*  is_mol_raw    = (const void*) d_in[2];
    const float* pos           = (const float*)d_in[3];
    const int*   time_step     = (const int*)  d_in[4];
    const float* embed_table   = (const float*)d_in[5];
    const float* atom_feat     = (const float*)d_in[6];
    const float* time_table    = (const float*)d_in[7];
    const float* w1            = (const float*)d_in[8];
    const float* b1            = (const float*)d_in[9];
    const float* w2            = (const float*)d_in[10];
    const float* b2            = (const float*)d_in[11];
    const float* pos_emb_w     = (const float*)d_in[12];
    const float* pos_feature_w = (const float*)d_in[13];

    float* out = (float*)d_out;
    char*  ws  = (char*)d_ws;

    // Workspace overlay (~7.54 MB, unchanged from proven layout):
    //   [0,2MB):      W1t bf16 (dead after K2) -> Ebf bf16 (K3 out)
    //   [2MB,4MB):    H bf16
    //   [4MB,6MB):    W2t bf16
    //   [6MB,+320KB): embed_bf
    //   [6.5MB,+1MB): atom_bf
    //   [7.5MB,..):   V fp32[1024] | sSg fp32[8192] | is_mol int[8]
    unsigned short* W1t      = (unsigned short*)(ws);
    unsigned short* Ebf      = (unsigned short*)(ws);
    unsigned short* H        = (unsigned short*)(ws + (2u << 20));
    unsigned short* W2t      = (unsigned short*)(ws + (4u << 20));
    unsigned short* embed_bf = (unsigned short*)(ws + (6u << 20));
    unsigned short* atom_bf  = (unsigned short*)(ws + (6u << 20) + (512u << 10));
    char*           base7    = ws + (7u << 20) + (512u << 10);
    float*          V        = (float*)(base7);
    float*          sSg      = (float*)(base7 + (4u << 10));
    int*            is_mol_r = (int*)  (base7 + (36u << 10));

    prep<<<3237, 256, 0, stream>>>(w1, w2, embed_table, atom_feat,
                                   pos_emb_w, pos_feature_w,
                                   is_mol_raw, token_id, pos,
                                   W1t, W2t, embed_bf, atom_bf,
                                   V, is_mol_r, sSg);

    gemm1k<<<256, 256, 0, stream>>>(time_table, W1t, b1, H);

    gemm2k<<<256, 256, 0, stream>>>(H, W2t, b2, Ebf);

    assemble<<<1024, 256, 0, stream>>>(token_id, node_attr, time_step,
                                       embed_bf, atom_bf, Ebf, V, sSg,
                                       is_mol_r, out);
}

// Round 2
// 146.452 us; speedup vs baseline: 1.0532x; 1.0532x over previous
//
#include <hip/hip_runtime.h>
#include <hip/hip_bf16.h>
#include <math.h>

// Problem constants (match reference)
#define BB 8
#define LL 1024
#define DD 1024
#define KK 128
#define NTS 1000
#define SCALE 0.08838834764831845f                 // 128^-0.5

typedef __attribute__((ext_vector_type(8))) short short8;   // 8 bf16 = 4 VGPRs
typedef __attribute__((ext_vector_type(4))) float f32x4;    // MFMA accumulator

__device__ __forceinline__ unsigned short f2bf(float x) {
    __hip_bfloat16 h = __float2bfloat16(x);   // RTNE
    return *reinterpret_cast<unsigned short*>(&h);
}
__device__ __forceinline__ float bf2f(unsigned short u) {
    return __uint_as_float(((unsigned int)u) << 16);
}

// async global->LDS, 16B per lane, LDS dest = wave-uniform base + lane*16
__device__ __forceinline__ void gload_lds16(const void* g, void* l) {
    __builtin_amdgcn_global_load_lds(
        (const __attribute__((address_space(1))) unsigned int*)g,
        (__attribute__((address_space(3))) unsigned int*)l, 16, 0, 0);
}

// D1 LDS union: gemm1 staging (48 KB) / attention keys (16 KB) / transpose tile
union SMemD1 {
    struct {
        unsigned short As[2][64 * 64];   // bf16 A tiles, 8 KB each
        float          Bs[2][64 * 64];   // fp32 w1 tiles [k][n], 16 KB each
    } g;                                 // 49152 B total
    float4 keys[LL];                     // 16384 B (attention)
    float  tile[32][33];                 // 4224 B  (transpose)
};

// ---------------------------------------------------------------------------
// 32x32 transpose+cast tile: in fp32 [1024,1024] -> out[n][k] bf16 (R6-proven)
// ---------------------------------------------------------------------------
__device__ __forceinline__ void transpose_tile(
    const float* __restrict__ in, unsigned short* __restrict__ out,
    int idx, float (*tile)[33])
{
    const int tid = threadIdx.x;
    const int bx = (idx & 31) * 32, by = (idx >> 5) * 32;
    const int tx = tid & 31, ty = tid >> 5;   // 32 x 8
    #pragma unroll
    for (int r = 0; r < 32; r += 8)
        tile[ty + r][tx] = in[(size_t)(by + ty + r) * DD + bx + tx];
    __syncthreads();
    #pragma unroll
    for (int r = 0; r < 32; r += 8)
        out[(size_t)(bx + ty + r) * DD + by + tx] = f2bf(tile[tx][ty + r]);
    __syncthreads();
}

// ---------------------------------------------------------------------------
// gemm1: silu(time_table @ w1 + b1) -> H bf16, 64x64 tile, BK=64, dbuf.
// TRANSPOSE-FREE B: w1 staged as fp32 [k][n] via linear global_load_lds;
// B-fragment built with 8 x ds_read_b32 (stride 64 floats) + f2bf. 4-way
// bank conflict on those scalar reads (quads differ in k, same bank) costs
// ~1.58x on ~1/3 of LDS ops -- accepted to delete the W1t dispatch.
// A: fp32 time_table reg-staged + cast, rows clamped at NTS-1 (junk rows
// never gathered downstream). XOR swizzle on As only (b128 reads).
// 2-phase pipeline: stage(t+1) issued before compute(t), one vmcnt(0)+barrier
// per K-step (T3-min).
// ---------------------------------------------------------------------------
__device__ __forceinline__ void gemm1_tile(
    const float* __restrict__ Af, const float* __restrict__ W1,
    const float* __restrict__ bias, unsigned short* __restrict__ Cout,
    int mBase, int nBase, SMemD1& sm)
{
    const int tid  = threadIdx.x;
    const int lane = tid & 63, wave = tid >> 6;
    const int wm = wave >> 1, wn = wave & 1;
    const int quad = lane >> 4, l16 = lane & 15;

    // ---- A staging geometry (proven in R1): 2 chunks/wave, 8 rows/chunk ----
    const int cA0 = wave * 2;
    int rAc[2], kElA[2];
    #pragma unroll
    for (int i = 0; i < 2; ++i) {
        const int c   = cA0 + i;
        const int o   = c * 1024 + lane * 16;
        const int row = o >> 7;
        const int lin = o ^ ((row & 7) << 4);
        int r = mBase + row;
        rAc[i]  = r < NTS ? r : NTS - 1;
        kElA[i] = (lin & 127) >> 1;
    }

    // ---- B staging geometry: 4 chunks/wave, 4 rows(k)/chunk, linear ----
    // chunk c covers LDS bytes [c*1024, c*1024+1024): rows 4c..4c+3, 256B/row.
    const int cB0 = wave * 4;
    const int rB  = lane >> 4;            // row within chunk
    const int cBb = (lane & 15) * 4;      // col element offset (fp32)

    f32x4 acc[2][2];
    #pragma unroll
    for (int i = 0; i < 2; ++i)
        #pragma unroll
        for (int j = 0; j < 2; ++j)
            acc[i][j] = (f32x4){0.f, 0.f, 0.f, 0.f};

    float4 pa[2][2];

    // ---- prologue: stage tile 0 ----
    #pragma unroll
    for (int i = 0; i < 2; ++i) {
        const float* p = Af + (size_t)rAc[i] * DD + kElA[i];
        pa[i][0] = *(const float4*)p;
        pa[i][1] = *(const float4*)(p + 4);
    }
    #pragma unroll
    for (int i = 0; i < 4; ++i) {
        const int c = cB0 + i;
        gload_lds16(W1 + (size_t)(4 * c + rB) * DD + nBase + cBb,
                    (char*)&sm.g.Bs[0][0] + c * 1024);
    }
    asm volatile("s_waitcnt vmcnt(0)" ::: "memory");
    #pragma unroll
    for (int i = 0; i < 2; ++i) {
        short8 s;
        s[0] = f2bf(pa[i][0].x); s[1] = f2bf(pa[i][0].y);
        s[2] = f2bf(pa[i][0].z); s[3] = f2bf(pa[i][0].w);
        s[4] = f2bf(pa[i][1].x); s[5] = f2bf(pa[i][1].y);
        s[6] = f2bf(pa[i][1].z); s[7] = f2bf(pa[i][1].w);
        *(short8*)((char*)&sm.g.As[0][0] + (cA0 + i) * 1024 + lane * 16) = s;
    }
    __syncthreads();

    int buf = 0;
    for (int t = 0; t < 16; ++t) {
        const int kn = (t + 1) * 64;
        if (t < 15) {
            #pragma unroll
            for (int i = 0; i < 2; ++i) {
                const float* p = Af + (size_t)rAc[i] * DD + kn + kElA[i];
                pa[i][0] = *(const float4*)p;
                pa[i][1] = *(const float4*)(p + 4);
            }
            #pragma unroll
            for (int i = 0; i < 4; ++i) {
                const int c = cB0 + i;
                gload_lds16(W1 + (size_t)(kn + 4 * c + rB) * DD + nBase + cBb,
                            (char*)&sm.g.Bs[buf ^ 1][0] + c * 1024);
            }
        }

        // compute on buf
        #pragma unroll
        for (int kk = 0; kk < 64; kk += 32) {
            short8 a[2], b[2];
            #pragma unroll
            for (int i = 0; i < 2; ++i) {
                const int row  = wm * 32 + i * 16 + l16;
                const int byte = ((row << 7) + ((kk + quad * 8) << 1))
                                 ^ ((row & 7) << 4);
                a[i] = *(const short8*)((const char*)&sm.g.As[buf][0] + byte);
            }
            #pragma unroll
            for (int j = 0; j < 2; ++j) {
                const int ncol = wn * 32 + j * 16 + l16;
                const float* bp = &sm.g.Bs[buf][(kk + quad * 8) * 64 + ncol];
                short8 bf;
                #pragma unroll
                for (int e = 0; e < 8; ++e) bf[e] = f2bf(bp[e * 64]);
                b[j] = bf;
            }
            #pragma unroll
            for (int i = 0; i < 2; ++i)
                #pragma unroll
                for (int j = 0; j < 2; ++j)
                    acc[i][j] = __builtin_amdgcn_mfma_f32_16x16x32_bf16(
                                    a[i], b[j], acc[i][j], 0, 0, 0);
        }

        if (t < 15) {
            asm volatile("s_waitcnt vmcnt(0)" ::: "memory");
            #pragma unroll
            for (int i = 0; i < 2; ++i) {
                short8 s;
                s[0] = f2bf(pa[i][0].x); s[1] = f2bf(pa[i][0].y);
                s[2] = f2bf(pa[i][0].z); s[3] = f2bf(pa[i][0].w);
                s[4] = f2bf(pa[i][1].x); s[5] = f2bf(pa[i][1].y);
                s[6] = f2bf(pa[i][1].z); s[7] = f2bf(pa[i][1].w);
                *(short8*)((char*)&sm.g.As[buf ^ 1][0] + (cA0 + i) * 1024 + lane * 16) = s;
            }
            __syncthreads();
        }
        buf ^= 1;
    }

    // epilogue: C/D layout col = lane&15, row = quad*4 + reg  [m89-verified]
    #pragma unroll
    for (int j = 0; j < 2; ++j) {
        const int col = nBase + wn * 32 + j * 16 + l16;
        const float bv = bias[col];
        #pragma unroll
        for (int i = 0; i < 2; ++i) {
            #pragma unroll
            for (int r = 0; r < 4; ++r) {
                const int row = mBase + wm * 32 + i * 16 + quad * 4 + r;
                float val = acc[i][j][r] + bv;
                val = val / (1.0f + __expf(-val));          // silu
                Cout[(size_t)row * DD + col] = f2bf(val);
            }
        }
    }
}

// ---------------------------------------------------------------------------
// D1: gemm1 (blocks 0..255, launched first) + ALL gemm1-independent work
// co-scheduled in its shadow (round-0-proven pattern, m114):
//   256..1279  : w2 -> W2t transpose tiles
//   1280..1439 : embed cast fp32->bf16
//   1440..1951 : atom cast fp32->bf16
//   1952..1955 : v[d] = sum_c pos_emb_w[c] * pos_feature_w[c,d]
//   1956       : is_molecule dtype resolve
//   1957..2468 : attention scalars (512 blocks x 16 queries -> sSg)
// ---------------------------------------------------------------------------
__global__ __launch_bounds__(256) void d1(
    const float* __restrict__ time_table,
    const float* __restrict__ w1,
    const float* __restrict__ b1,
    const float* __restrict__ w2,
    const float* __restrict__ embed_f,
    const float* __restrict__ atom_f,
    const float* __restrict__ pos_emb_w,
    const float* __restrict__ pos_feature_w,
    const void*  __restrict__ is_mol_raw,
    const int*   __restrict__ token_id,
    const float* __restrict__ pos,
    unsigned short* __restrict__ H,
    unsigned short* __restrict__ W2t,
    unsigned short* __restrict__ embed_bf,
    unsigned short* __restrict__ atom_bf,
    float* __restrict__ v,
    int*   __restrict__ is_mol_out,
    float* __restrict__ sSg)
{
    __shared__ SMemD1 sm;
    const int blk = blockIdx.x;
    const int tid = threadIdx.x;

    if (blk < 256) {
        // XCD-bijective swizzle (256 % 8 == 0)
        const int b = (blk & 7) * 32 + (blk >> 3);
        gemm1_tile(time_table, w1, b1, H, (b >> 4) * 64, (b & 15) * 64, sm);
    } else if (blk < 1280) {
        transpose_tile(w2, W2t, blk - 256, sm.tile);
    } else if (blk < 1440) {
        const int e = ((blk - 1280) * 256 + tid) * 4;    // < 160*1024
        float4 vv = *(const float4*)&embed_f[e];
        ushort4 o = { f2bf(vv.x), f2bf(vv.y), f2bf(vv.z), f2bf(vv.w) };
        *(ushort4*)&embed_bf[e] = o;
    } else if (blk < 1952) {
        const int e = ((blk - 1440) * 256 + tid) * 4;    // < 512*1024
        float4 vv = *(const float4*)&atom_f[e];
        ushort4 o = { f2bf(vv.x), f2bf(vv.y), f2bf(vv.z), f2bf(vv.w) };
        *(ushort4*)&atom_bf[e] = o;
    } else if (blk < 1956) {
        const int d = (blk - 1952) * 256 + tid;          // < 1024
        float acc = 0.0f;
        #pragma unroll 4
        for (int c = 0; c < KK; ++c)
            acc += pos_emb_w[c] * pos_feature_w[c * DD + d];
        v[d] = acc;
    } else if (blk == 1956) {
        if (tid == 0) {
            const int* ip = (const int*)is_mol_raw;
            const unsigned char* cp = (const unsigned char*)is_mol_raw;
            bool all_bin = true;
            for (int i = 0; i < BB; ++i) {
                int x = ip[i];
                if (x != 0 && x != 1) all_bin = false;
            }
            for (int i = 0; i < BB; ++i)
                is_mol_out[i] = all_bin ? (ip[i] != 0) : (cp[i] != 0);
        }
    } else {
        // Attention scalars: block handles 16 queries of one batch.
        // No-max softmax: valid scores in (0, 0.0884] so exp can't overflow;
        // masked keys contribute exactly 0.
        const int ab = blk - 1957;            // 0..511
        const int batch = ab >> 6;
        const int q0 = (ab & 63) * 16;
        const int lane = tid & 63, wave = tid >> 6;

        #pragma unroll
        for (int i = 0; i < 4; ++i) {
            const int k = tid + i * 256;
            const int t = batch * LL + k;
            const float x = pos[t * 3 + 0];
            const float y = pos[t * 3 + 1];
            const float z = pos[t * 3 + 2];
            const int tok = token_id[t];
            const float n = sqrtf(x * x + y * y + z * z);
            sm.keys[k] = make_float4(x, y, z, tok == 0 ? -1.0f : n);
        }
        __syncthreads();

        #pragma unroll
        for (int qi = 0; qi < 4; ++qi) {
            const int ql = wave * 4 + qi;
            const float4 qk = sm.keys[q0 + ql];
            float lsum = 0.0f, lws = 0.0f;
            #pragma unroll 4
            for (int i = 0; i < 16; ++i) {
                const float4 kd = sm.keys[lane + i * 64];
                const float dx = qk.x - kd.x, dy = qk.y - kd.y, dz = qk.z - kd.z;
                const float dn = sqrtf(dx * dx + dy * dy + dz * dz);
                const float e = __expf(SCALE / (dn + 1.0f));
                const bool valid = kd.w >= 0.0f;
                const float ev = valid ? e : 0.0f;
                lsum += ev;
                lws  += ev * (valid ? kd.w : 0.0f);
            }
            #pragma unroll
            for (int off = 32; off > 0; off >>= 1) {
                lsum += __shfl_xor(lsum, off);
                lws  += __shfl_xor(lws,  off);
            }
            if (lane == 0)
                sSg[batch * LL + q0 + ql] = (qk.w < 0.0f) ? 0.0f : (lws / lsum);
        }
    }
}

// ---------------------------------------------------------------------------
// D2: gemm2 = H @ W2 + b2 -> Ebf bf16 (R1-proven gemm64 bf16 path, verbatim).
// ---------------------------------------------------------------------------
__global__ __launch_bounds__(256) void gemm2k(
    const unsigned short* __restrict__ Ab,
    const unsigned short* __restrict__ Bt,
    const float* __restrict__ bias,
    unsigned short* __restrict__ Cout)
{
    __shared__ __align__(16) unsigned short As[2][64 * 64];
    __shared__ __align__(16) unsigned short Bs[2][64 * 64];

    const int b = (blockIdx.x & 7) * 32 + (blockIdx.x >> 3);
    const int mBase = (b >> 4) * 64, nBase = (b & 15) * 64;

    const int tid  = threadIdx.x;
    const int lane = tid & 63, wave = tid >> 6;
    const int wm = wave >> 1, wn = wave & 1;
    const int quad = lane >> 4, l16 = lane & 15;
    const int c0 = wave * 2;

    int rowA[2], kEl[2];
    #pragma unroll
    for (int i = 0; i < 2; ++i) {
        const int c   = c0 + i;
        const int o   = c * 1024 + lane * 16;
        const int row = o >> 7;
        const int lin = o ^ ((row & 7) << 4);
        rowA[i] = row;
        kEl[i]  = (lin & 127) >> 1;
    }

    f32x4 acc[2][2];
    #pragma unroll
    for (int i = 0; i < 2; ++i)
        #pragma unroll
        for (int j = 0; j < 2; ++j)
            acc[i][j] = (f32x4){0.f, 0.f, 0.f, 0.f};

    #pragma unroll
    for (int i = 0; i < 2; ++i) {
        gload_lds16(Ab + (size_t)(mBase + rowA[i]) * DD + kEl[i],
                    (char*)&As[0][0] + (c0 + i) * 1024);
        gload_lds16(Bt + (size_t)(nBase + rowA[i]) * DD + kEl[i],
                    (char*)&Bs[0][0] + (c0 + i) * 1024);
    }
    asm volatile("s_waitcnt vmcnt(0)" ::: "memory");
    __syncthreads();

    int buf = 0;
    for (int t = 0; t < 16; ++t) {
        const int kn = (t + 1) * 64;
        if (t < 15) {
            #pragma unroll
            for (int i = 0; i < 2; ++i) {
                gload_lds16(Ab + (size_t)(mBase + rowA[i]) * DD + kn + kEl[i],
                            (char*)&As[buf ^ 1][0] + (c0 + i) * 1024);
                gload_lds16(Bt + (size_t)(nBase + rowA[i]) * DD + kn + kEl[i],
                            (char*)&Bs[buf ^ 1][0] + (c0 + i) * 1024);
            }
        }

        #pragma unroll
        for (int kk = 0; kk < 64; kk += 32) {
            short8 a[2], bb[2];
            #pragma unroll
            for (int i = 0; i < 2; ++i) {
                const int row  = wm * 32 + i * 16 + l16;
                const int byte = ((row << 7) + ((kk + quad * 8) << 1))
                                 ^ ((row & 7) << 4);
                a[i] = *(const short8*)((const char*)&As[buf][0] + byte);
            }
            #pragma unroll
            for (int j = 0; j < 2; ++j) {
                const int row  = wn * 32 + j * 16 + l16;
                const int byte = ((row << 7) + ((kk + quad * 8) << 1))
                                 ^ ((row & 7) << 4);
                bb[j] = *(const short8*)((const char*)&Bs[buf][0] + byte);
            }
            #pragma unroll
            for (int i = 0; i < 2; ++i)
                #pragma unroll
                for (int j = 0; j < 2; ++j)
                    acc[i][j] = __builtin_amdgcn_mfma_f32_16x16x32_bf16(
                                    a[i], bb[j], acc[i][j], 0, 0, 0);
        }

        if (t < 15) {
            asm volatile("s_waitcnt vmcnt(0)" ::: "memory");
            __syncthreads();
        }
        buf ^= 1;
    }

    #pragma unroll
    for (int j = 0; j < 2; ++j) {
        const int col = nBase + wn * 32 + j * 16 + l16;
        const float bv = bias[col];
        #pragma unroll
        for (int i = 0; i < 2; ++i) {
            #pragma unroll
            for (int r = 0; r < 4; ++r) {
                const int row = mBase + wm * 32 + i * 16 + quad * 4 + r;
                Cout[(size_t)row * DD + col] = f2bf(acc[i][j][r] + bv);
            }
        }
    }
}

// ---------------------------------------------------------------------------
// D3: gather/assemble (unchanged, R6-proven).
// ---------------------------------------------------------------------------
__global__ __launch_bounds__(256) void assemble(
    const int*   __restrict__ token_id,
    const int*   __restrict__ node_attr,
    const int*   __restrict__ time_step,
    const unsigned short* __restrict__ embed_bf,
    const unsigned short* __restrict__ atom_bf,
    const unsigned short* __restrict__ Ebf,
    const float* __restrict__ v,
    const float* __restrict__ sSg,
    const int*   __restrict__ is_mol,
    float* __restrict__ out)
{
    const int blk   = blockIdx.x;
    const int batch = blk >> 7;
    const int q0    = (blk & 127) << 3;
    const int tid   = threadIdx.x;

    const int im   = is_mol[batch];
    const int half = tid >> 7;
    const int tl   = tid & 127;
    const int j    = tl * 8;
    const float4 v0 = *(const float4*)&v[j];
    const float4 v1 = *(const float4*)&v[j + 4];

    #pragma unroll
    for (int qp = 0; qp < 4; ++qp) {
        const int ql  = qp * 2 + half;
        const int t   = batch * LL + q0 + ql;
        const int tok = token_id[t];
        const int ts  = time_step[t];
        const float s = sSg[t];

        float o[8];
        short8 eb = *(const short8*)&embed_bf[(size_t)tok * DD + j];
        #pragma unroll
        for (int d = 0; d < 8; ++d) o[d] = bf2f((unsigned short)eb[d]);

        if (im) {
            #pragma unroll
            for (int f = 1; f < 9; ++f) {
                const int a = node_attr[t * 9 + f];
                short8 ab = *(const short8*)&atom_bf[(size_t)a * DD + j];
                #pragma unroll
                for (int d = 0; d < 8; ++d) o[d] += bf2f((unsigned short)ab[d]);
            }
        }
        short8 er = *(const short8*)&Ebf[(size_t)ts * DD + j];
        #pragma unroll
        for (int d = 0; d < 8; ++d) o[d] += bf2f((unsigned short)er[d]);

        o[0] += s * v0.x; o[1] += s * v0.y; o[2] += s * v0.z; o[3] += s * v0.w;
        o[4] += s * v1.x; o[5] += s * v1.y; o[6] += s * v1.z; o[7] += s * v1.w;

        float4 wlo = {o[0], o[1], o[2], o[3]};
        float4 whi = {o[4], o[5], o[6], o[7]};
        *(float4*)&out[(size_t)t * DD + j]     = wlo;
        *(float4*)&out[(size_t)t * DD + j + 4] = whi;
    }

    if (tid < 8) {
        const int t = batch * LL + q0 + tid;
        out[(size_t)BB * LL * DD + t] = (token_id[t] == 0) ? 1.0f : 0.0f;
    }
}

// ---------------------------------------------------------------------------
extern "C" void kernel_launch(void* const* d_in, const int* in_sizes, int n_in,
                              void* d_out, int out_size, void* d_ws, size_t ws_size,
                              hipStream_t stream)
{
    const int*   token_id      = (const int*)  d_in[0];
    const int*   node_attr     = (const int*)  d_in[1];
    const void*  is_mol_raw    = (const void*) d_in[2];
    const float* pos           = (const float*)d_in[3];
    const int*   time_step     = (const int*)  d_in[4];
    const float* embed_table   = (const float*)d_in[5];
    const float* atom_feat     = (const float*)d_in[6];
    const float* time_table    = (const float*)d_in[7];
    const float* w1            = (const float*)d_in[8];
    const float* b1            = (const float*)d_in[9];
    const float* w2            = (const float*)d_in[10];
    const float* b2            = (const float*)d_in[11];
    const float* pos_emb_w     = (const float*)d_in[12];
    const float* pos_feature_w = (const float*)d_in[13];

    float* out = (float*)d_out;
    char*  ws  = (char*)d_ws;

    // Workspace overlay (~7.54 MB, same proven layout; W1t slot now free):
    //   [0,2MB):      Ebf bf16 (D2 out)
    //   [2MB,4MB):    H bf16
    //   [4MB,6MB):    W2t bf16
    //   [6MB,+320KB): embed_bf
    //   [6.5MB,+1MB): atom_bf
    //   [7.5MB,..):   V fp32[1024] | sSg fp32[8192] | is_mol int[8]
    unsigned short* Ebf      = (unsigned short*)(ws);
    unsigned short* H        = (unsigned short*)(ws + (2u << 20));
    unsigned short* W2t      = (unsigned short*)(ws + (4u << 20));
    unsigned short* embed_bf = (unsigned short*)(ws + (6u << 20));
    unsigned short* atom_bf  = (unsigned short*)(ws + (6u << 20) + (512u << 10));
    char*           base7    = ws + (7u << 20) + (512u << 10);
    float*          V        = (float*)(base7);
    float*          sSg      = (float*)(base7 + (4u << 10));
    int*            is_mol_r = (int*)  (base7 + (36u << 10));

    d1<<<2469, 256, 0, stream>>>(time_table, w1, b1, w2, embed_table,
                                 atom_feat, pos_emb_w, pos_feature_w,
                                 is_mol_raw, token_id, pos,
                                 H, W2t, embed_bf, atom_bf, V, is_mol_r, sSg);

    gemm2k<<<256, 256, 0, stream>>>(H, W2t, b2, Ebf);

    assemble<<<1024, 256, 0, stream>>>(token_id, node_attr, time_step,
                                       embed_bf, atom_bf, Ebf, V, sSg,
                                       is_mol_r, out);
}